// Round 4
// baseline (124.239 us; speedup 1.0000x reference)
//
#include <hip/hip_runtime.h>

// CrossAttention collapses algebraically:
//   age is broadcast across the pixel dim BEFORE the K/V projections, so
//   k[b,m,:] and v[b,m,:] are constant over m => every score row is constant
//   => softmax is exactly uniform => attended[b,n,:] = v_vec[b,:]
//   => out[b,n,d] = pixel[b,n,d] + age[b,:]·Wv[:,d] + bv[d]
// Q/Wq/bq/Wk/bk do not affect the output.
//
// Single fused kernel: each block recomputes v for its 4 columns/thread
// (Wv served from L2/L3: 512 blocks x 384 KB = ~200 MB L2 traffic, ~6 us,
// overlapped), then streams 32 rows of pixel+v -> out with nontemporal
// load/store (read-once / write-once data, keep L2 clean).

#define PIXEL_DIM 768
#define AGE_DIM   128
#define BB        8
#define NN        2048

#define ROW4        (PIXEL_DIM / 4)  // 192 float4 per row
#define CHUNKS      64               // blocks per batch
#define ROWS_PER_BLOCK (NN / CHUNKS) // 32

// Native Clang vector type: accepted by __builtin_nontemporal_* (HIP's float4
// is a struct and is rejected). Same 16B layout -> global_load_dwordx4.
typedef float fvec4 __attribute__((ext_vector_type(4)));

__global__ void __launch_bounds__(ROW4)
ca_fused(const fvec4* __restrict__ pixel,
         const float* __restrict__ age,
         const fvec4* __restrict__ Wv,      // [128, 192] as fvec4
         const fvec4* __restrict__ bv,      // [192] as fvec4
         fvec4* __restrict__ out) {
    const int t = threadIdx.x;              // 0..191 -> columns 4t..4t+3
    const int b = blockIdx.y;               // 0..7
    const int n0 = blockIdx.x * ROWS_PER_BLOCK;

    // --- per-block GEMV for this thread's 4 columns ---
    const float* ab = age + b * AGE_DIM;    // lane-uniform -> s_loads
    fvec4 v = bv[t];
    #pragma unroll 8
    for (int a = 0; a < AGE_DIM; ++a) {
        const float aa = ab[a];
        const fvec4 w = Wv[a * ROW4 + t];   // coalesced; L2/L3-resident
        v.x = fmaf(aa, w.x, v.x);
        v.y = fmaf(aa, w.y, v.y);
        v.z = fmaf(aa, w.z, v.z);
        v.w = fmaf(aa, w.w, v.w);
    }

    // --- stream 32 rows: out = pixel + v ---
    long base = ((long)b * NN + n0) * ROW4 + t;
    #pragma unroll 8
    for (int r = 0; r < ROWS_PER_BLOCK; ++r) {
        fvec4 p = __builtin_nontemporal_load(&pixel[base]);
        fvec4 o = p + v;
        __builtin_nontemporal_store(o, &out[base]);
        base += ROW4;                       // next row, same column
    }
}

extern "C" void kernel_launch(void* const* d_in, const int* in_sizes, int n_in,
                              void* d_out, int out_size, void* d_ws, size_t ws_size,
                              hipStream_t stream) {
    const float* pixel = (const float*)d_in[0];  // [8, 2048, 768]
    const float* age   = (const float*)d_in[1];  // [8, 128]
    // d_in[2..5] = Wq, bq, Wk, bk  -- unused (see header comment)
    const float* Wv    = (const float*)d_in[6];  // [128, 768]
    const float* bv    = (const float*)d_in[7];  // [768]
    float* out = (float*)d_out;
    (void)d_ws; (void)ws_size;

    dim3 grid(CHUNKS, BB);                  // 512 blocks, 2/CU
    ca_fused<<<grid, ROW4, 0, stream>>>((const fvec4*)pixel, age,
                                        (const fvec4*)Wv, (const fvec4*)bv,
                                        (fvec4*)out);
}

// Round 5
// 118.143 us; speedup vs baseline: 1.0516x; 1.0516x over previous
//
#include <hip/hip_runtime.h>

// CrossAttention collapses algebraically:
//   age is broadcast across the pixel dim BEFORE the K/V projections, so
//   k[b,m,:] and v[b,m,:] are constant over m => every score row is constant
//   => softmax is exactly uniform => attended[b,n,:] = v_vec[b,:]
//   => out[b,n,d] = pixel[b,n,d] + age[b,:]·Wv[:,d] + bv[d]
// Q/Wq/bq/Wk/bk do not affect the output.
//
// Single fused kernel, PLAIN cached loads/stores (R4 showed nontemporal
// regresses ~6.5us: pixel is L3-resident after the harness restore-copy, and
// cached stores can retire dirty-in-L3 instead of draining to HBM in-window).

#define PIXEL_DIM 768
#define AGE_DIM   128
#define BB        8
#define NN        2048

#define ROW4        (PIXEL_DIM / 4)  // 192 float4 per row
#define CHUNKS      64               // blocks per batch
#define ROWS_PER_BLOCK (NN / CHUNKS) // 32

typedef float fvec4 __attribute__((ext_vector_type(4)));

__global__ void __launch_bounds__(ROW4)
ca_fused(const fvec4* __restrict__ pixel,
         const float* __restrict__ age,
         const fvec4* __restrict__ Wv,      // [128, 192] as fvec4
         const fvec4* __restrict__ bv,      // [192] as fvec4
         fvec4* __restrict__ out) {
    const int t = threadIdx.x;              // 0..191 -> columns 4t..4t+3
    const int b = blockIdx.y;               // 0..7
    const int n0 = blockIdx.x * ROWS_PER_BLOCK;

    // --- per-block GEMV for this thread's 4 columns (Wv from L2/L3) ---
    const float* ab = age + b * AGE_DIM;    // lane-uniform -> s_loads
    fvec4 v = bv[t];
    #pragma unroll 8
    for (int a = 0; a < AGE_DIM; ++a) {
        const float aa = ab[a];
        const fvec4 w = Wv[a * ROW4 + t];   // coalesced
        v.x = fmaf(aa, w.x, v.x);
        v.y = fmaf(aa, w.y, v.y);
        v.z = fmaf(aa, w.z, v.z);
        v.w = fmaf(aa, w.w, v.w);
    }

    // --- stream 32 rows: out = pixel + v (cached: pixel is L3-resident) ---
    long base = ((long)b * NN + n0) * ROW4 + t;
    #pragma unroll 8
    for (int r = 0; r < ROWS_PER_BLOCK; ++r) {
        fvec4 p = pixel[base];
        out[base] = p + v;
        base += ROW4;                       // next row, same column
    }
}

extern "C" void kernel_launch(void* const* d_in, const int* in_sizes, int n_in,
                              void* d_out, int out_size, void* d_ws, size_t ws_size,
                              hipStream_t stream) {
    const float* pixel = (const float*)d_in[0];  // [8, 2048, 768]
    const float* age   = (const float*)d_in[1];  // [8, 128]
    // d_in[2..5] = Wq, bq, Wk, bk  -- unused (see header comment)
    const float* Wv    = (const float*)d_in[6];  // [128, 768]
    const float* bv    = (const float*)d_in[7];  // [768]
    float* out = (float*)d_out;
    (void)d_ws; (void)ws_size;

    dim3 grid(CHUNKS, BB);                  // 512 blocks, 2/CU
    ca_fused<<<grid, ROW4, 0, stream>>>((const fvec4*)pixel, age,
                                        (const fvec4*)Wv, (const fvec4*)bv,
                                        (fvec4*)out);
}